// Round 1
// baseline (579.236 us; speedup 1.0000x reference)
//
#include <hip/hip_runtime.h>
#include <math.h>

// ---------------------------------------------------------------------------
// Kernel A: fused model1 MLP (318->50->20->20, ReLU) + SelfAttentionPooling
// over T=128 for two (b,g) groups per block.
// Grid: 2048 blocks (= 4096 groups / 2), 256 threads (one thread per token).
// Writes r[(b*128+g)*20 + o] to workspace.
// ---------------------------------------------------------------------------
__global__ __launch_bounds__(256, 4)
void fused_mlp_pool_t(const float* __restrict__ x,
                      const float* __restrict__ W1a, const float* __restrict__ b1a,
                      const float* __restrict__ W1b, const float* __restrict__ b1b,
                      const float* __restrict__ W1c, const float* __restrict__ b1c,
                      const float* __restrict__ pW1, const float* __restrict__ pb1,
                      const float* __restrict__ pW2, const float* __restrict__ pb2,
                      float* __restrict__ rout)
{
    // x tile: 256 rows x 16 floats per chunk, row stride padded to 20 floats
    // (stride 20 -> ds_read_b128: 8 lanes cover all 32 banks, conflict-free)
    __shared__ __align__(16) float lds[256 * 20];   // 20 KB
    __shared__ float red_m[2][2];
    __shared__ float red_s[2][2];
    __shared__ float part[2][2][20];

    const int tid = threadIdx.x;
    // Block's 256 rows are contiguous: row r -> flat group bg = blockIdx.x*2 + (r>>7)
    const float* xblk = x + (size_t)blockIdx.x * (256 * 318);

    // ---- K-tail (k = 304..317, 14 floats) straight into registers, issued early
    const float* xrow = xblk + (size_t)tid * 318;
    float xt[14];
    #pragma unroll
    for (int q = 0; q < 7; ++q) {
        float2 v = *(const float2*)(xrow + 304 + 2 * q);
        xt[2 * q] = v.x; xt[2 * q + 1] = v.y;
    }

    // ---- layer-1 accumulators (static indexing only)
    float acc[50];
    #pragma unroll
    for (int o = 0; o < 50; ++o) acc[o] = b1a[o];

    // ---- prefetch chunk 0 into registers (coalesced: 8 lanes per 64B row-chunk)
    float2 g[8];
    #pragma unroll
    for (int j = 0; j < 8; ++j) {
        int f = j * 256 + tid; int row = f >> 3, q = f & 7;
        g[j] = *(const float2*)(xblk + (size_t)row * 318 + 2 * q);
    }

    // ---- main loop: 19 chunks of 16 floats (k = 0..303)
    for (int c = 0; c < 19; ++c) {
        // write prefetched chunk to LDS
        #pragma unroll
        for (int j = 0; j < 8; ++j) {
            int f = j * 256 + tid; int row = f >> 3, q = f & 7;
            *(float2*)&lds[row * 20 + 2 * q] = g[j];
        }
        __syncthreads();
        // issue next chunk's global loads (overlap with compute below)
        if (c + 1 < 19) {
            const int k0n = (c + 1) * 16;
            #pragma unroll
            for (int j = 0; j < 8; ++j) {
                int f = j * 256 + tid; int row = f >> 3, q = f & 7;
                g[j] = *(const float2*)(xblk + (size_t)row * 318 + k0n + 2 * q);
            }
        }
        // compute: 16 k-values x 50 outputs; W via uniform (scalar) loads
        const int k0 = c * 16;
        const float4* lrow = (const float4*)&lds[tid * 20];
        #pragma unroll
        for (int k4 = 0; k4 < 4; ++k4) {
            float4 xv = lrow[k4];
            const float* wp = W1a + k0 + 4 * k4;
            #pragma unroll
            for (int o = 0; o < 50; ++o) {
                const float* w = wp + o * 318;
                float a = acc[o];
                a = fmaf(xv.x, w[0], a);
                a = fmaf(xv.y, w[1], a);
                a = fmaf(xv.z, w[2], a);
                a = fmaf(xv.w, w[3], a);
                acc[o] = a;
            }
        }
        __syncthreads();
    }

    // ---- K-tail contribution + ReLU
    #pragma unroll
    for (int o = 0; o < 50; ++o) {
        const float* w = W1a + o * 318 + 304;
        float a = acc[o];
        #pragma unroll
        for (int j = 0; j < 14; ++j) a = fmaf(xt[j], w[j], a);
        acc[o] = fmaxf(a, 0.0f);
    }

    // ---- layer 2: 50 -> 20, ReLU
    float h2[20];
    #pragma unroll
    for (int o = 0; o < 20; ++o) {
        float a = b1b[o];
        const float* w = W1b + o * 50;
        #pragma unroll
        for (int i = 0; i < 50; ++i) a = fmaf(acc[i], w[i], a);
        h2[o] = fmaxf(a, 0.0f);
    }

    // ---- layer 3: 20 -> 20, ReLU
    float h3[20];
    #pragma unroll
    for (int o = 0; o < 20; ++o) {
        float a = b1c[o];
        const float* w = W1c + o * 20;
        #pragma unroll
        for (int i = 0; i < 20; ++i) a = fmaf(h2[i], w[i], a);
        h3[o] = fmaxf(a, 0.0f);
    }

    // ---- pooling score: 20 -> 10 (ReLU) -> 1
    float s = pb2[0];
    #pragma unroll
    for (int j = 0; j < 10; ++j) {
        float a = pb1[j];
        const float* w = pW1 + j * 20;
        #pragma unroll
        for (int i = 0; i < 20; ++i) a = fmaf(h3[i], w[i], a);
        s = fmaf(fmaxf(a, 0.0f), pW2[j], s);
    }

    // ---- softmax over T=128 (one group = half block = 2 waves)
    const int grp  = tid >> 7;
    const int wig  = (tid >> 6) & 1;
    const int lane = tid & 63;

    float m = s;
    #pragma unroll
    for (int d = 32; d > 0; d >>= 1) m = fmaxf(m, __shfl_xor(m, d));
    if (lane == 0) red_m[grp][wig] = m;
    __syncthreads();
    m = fmaxf(red_m[grp][0], red_m[grp][1]);

    float e = expf(s - m);
    float su = e;
    #pragma unroll
    for (int d = 32; d > 0; d >>= 1) su += __shfl_xor(su, d);
    if (lane == 0) red_s[grp][wig] = su;

    // weighted sum of h3 over tokens
    #pragma unroll
    for (int o = 0; o < 20; ++o) {
        float v = e * h3[o];
        #pragma unroll
        for (int d = 32; d > 0; d >>= 1) v += __shfl_xor(v, d);
        if (lane == 0) part[grp][wig][o] = v;
    }
    __syncthreads();

    if ((tid & 127) < 20) {
        int o = tid & 127;
        float den = red_s[grp][0] + red_s[grp][1];
        float num = part[grp][0][o] + part[grp][1][o];
        rout[(size_t)(blockIdx.x * 2 + grp) * 20 + o] = num / den;
    }
}

// ---------------------------------------------------------------------------
// Kernel B: SelfAttentionPooling over G=128, L2-normalize, model3 head.
// Grid: 32 blocks (one per batch), 128 threads (one per group).
// ---------------------------------------------------------------------------
__global__ __launch_bounds__(128, 4)
void pool_g_head(const float* __restrict__ r,
                 const float* __restrict__ qW1, const float* __restrict__ qb1,
                 const float* __restrict__ qW2, const float* __restrict__ qb2,
                 const float* __restrict__ W3a, const float* __restrict__ b3a,
                 const float* __restrict__ W3b, const float* __restrict__ b3b,
                 float* __restrict__ out)
{
    __shared__ float red_m[2];
    __shared__ float red_s[2];
    __shared__ float part[2][20];

    const int tid = threadIdx.x;           // g
    const int b = blockIdx.x;
    const float* rr = r + ((size_t)b * 128 + tid) * 20;

    float v[20];
    #pragma unroll
    for (int i = 0; i < 5; ++i) {
        float4 t = *(const float4*)(rr + 4 * i);
        v[4 * i] = t.x; v[4 * i + 1] = t.y; v[4 * i + 2] = t.z; v[4 * i + 3] = t.w;
    }

    float s = qb2[0];
    #pragma unroll
    for (int j = 0; j < 10; ++j) {
        float a = qb1[j];
        const float* w = qW1 + j * 20;
        #pragma unroll
        for (int i = 0; i < 20; ++i) a = fmaf(v[i], w[i], a);
        s = fmaf(fmaxf(a, 0.0f), qW2[j], s);
    }

    const int wig = tid >> 6, lane = tid & 63;
    float m = s;
    #pragma unroll
    for (int d = 32; d > 0; d >>= 1) m = fmaxf(m, __shfl_xor(m, d));
    if (lane == 0) red_m[wig] = m;
    __syncthreads();
    m = fmaxf(red_m[0], red_m[1]);

    float e = expf(s - m);
    float su = e;
    #pragma unroll
    for (int d = 32; d > 0; d >>= 1) su += __shfl_xor(su, d);
    if (lane == 0) red_s[wig] = su;

    #pragma unroll
    for (int o = 0; o < 20; ++o) {
        float val = e * v[o];
        #pragma unroll
        for (int d = 32; d > 0; d >>= 1) val += __shfl_xor(val, d);
        if (lane == 0) part[wig][o] = val;
    }
    __syncthreads();

    if (tid == 0) {
        float den = red_s[0] + red_s[1];
        float rb[20];
        float n2 = 0.0f;
        #pragma unroll
        for (int o = 0; o < 20; ++o) {
            rb[o] = (part[0][o] + part[1][o]) / den;
            n2 = fmaf(rb[o], rb[o], n2);
        }
        float nrm = fmaxf(sqrtf(n2), 1e-12f);
        #pragma unroll
        for (int o = 0; o < 20; ++o) rb[o] /= nrm;

        float accv = b3b[0];
        #pragma unroll
        for (int j = 0; j < 10; ++j) {
            float a = b3a[j];
            const float* w = W3a + j * 20;
            #pragma unroll
            for (int i = 0; i < 20; ++i) a = fmaf(rb[i], w[i], a);
            accv = fmaf(fmaxf(a, 0.0f), W3b[j], accv);
        }
        out[b] = accv;
    }
}

extern "C" void kernel_launch(void* const* d_in, const int* in_sizes, int n_in,
                              void* d_out, int out_size, void* d_ws, size_t ws_size,
                              hipStream_t stream) {
    const float* x   = (const float*)d_in[0];
    const float* W1a = (const float*)d_in[1];
    const float* b1a = (const float*)d_in[2];
    const float* W1b = (const float*)d_in[3];
    const float* b1b = (const float*)d_in[4];
    const float* W1c = (const float*)d_in[5];
    const float* b1c = (const float*)d_in[6];
    const float* pW1 = (const float*)d_in[7];
    const float* pb1 = (const float*)d_in[8];
    const float* pW2 = (const float*)d_in[9];
    const float* pb2 = (const float*)d_in[10];
    const float* qW1 = (const float*)d_in[11];
    const float* qb1 = (const float*)d_in[12];
    const float* qW2 = (const float*)d_in[13];
    const float* qb2 = (const float*)d_in[14];
    const float* W3a = (const float*)d_in[15];
    const float* b3a = (const float*)d_in[16];
    const float* W3b = (const float*)d_in[17];
    const float* b3b = (const float*)d_in[18];

    float* rws = (float*)d_ws;   // 4096 x 20 floats = 327 KB

    fused_mlp_pool_t<<<2048, 256, 0, stream>>>(
        x, W1a, b1a, W1b, b1b, W1c, b1c, pW1, pb1, pW2, pb2, rws);
    pool_g_head<<<32, 128, 0, stream>>>(
        rws, qW1, qb1, qW2, qb2, W3a, b3a, W3b, b3b, (float*)d_out);
}

// Round 2
// 353.531 us; speedup vs baseline: 1.6384x; 1.6384x over previous
//
#include <hip/hip_runtime.h>
#include <math.h>
#include <stdint.h>

typedef __attribute__((ext_vector_type(8))) short bf16x8;
typedef __attribute__((ext_vector_type(4))) float floatx4;

__device__ __forceinline__ unsigned short f32_to_bf16_rne(float f) {
    union { float f; uint32_t u; } v; v.f = f;
    uint32_t u = v.u;
    return (unsigned short)((u + 0x7fffu + ((u >> 16) & 1u)) >> 16);
}
__device__ __forceinline__ float bf16_to_f32(unsigned short h) {
    union { uint32_t u; float f; } v; v.u = ((uint32_t)h) << 16;
    return v.f;
}

// ---------------------------------------------------------------------------
// Prep: split W1a (50x318 fp32, row-major NxK) into hi/lo bf16 in the exact
// LDS image layout: [kstep 10][part 2][n 64][kp 40] bf16. Pads are zero.
// ---------------------------------------------------------------------------
__global__ void prep_w(const float* __restrict__ W1a, unsigned short* __restrict__ Bws) {
    for (int idx = threadIdx.x; idx < 10 * 2 * 64 * 40; idx += blockDim.x) {
        int kstep = idx / (2 * 64 * 40);
        int rem   = idx % (2 * 64 * 40);
        int part  = rem / (64 * 40);
        int rem2  = rem % (64 * 40);
        int n  = rem2 / 40;
        int kp = rem2 % 40;
        int k  = kstep * 32 + kp;
        float w = (n < 50 && kp < 32 && k < 318) ? W1a[n * 318 + k] : 0.0f;
        unsigned short hi = f32_to_bf16_rne(w);
        Bws[idx] = (part == 0) ? hi : f32_to_bf16_rne(w - bf16_to_f32(hi));
    }
}

// ---------------------------------------------------------------------------
// Kernel A: layer1 via bf16 MFMA (W hi+lo split), layers 2/3 + T-pooling fp32.
// Block: 256 threads (4 waves), 256 tokens (2 groups). Grid: 2048.
// ---------------------------------------------------------------------------
#define LDSA_BYTES (256 * 40 * 2)      // 20480 per buffer ([256][40] bf16)
#define LDSB_BYTES (2 * 64 * 40 * 2)   // 10240 per buffer (hi+lo [64][40] bf16)

__global__ __launch_bounds__(256, 2)
void fused_mlp_pool_t(const float* __restrict__ x,
                      const unsigned short* __restrict__ Bws,
                      const float* __restrict__ b1a,
                      const float* __restrict__ W1b, const float* __restrict__ b1b,
                      const float* __restrict__ W1c, const float* __restrict__ b1c,
                      const float* __restrict__ pW1, const float* __restrict__ pb1,
                      const float* __restrict__ pW2, const float* __restrict__ pb2,
                      float* __restrict__ rout)
{
    __shared__ __align__(16) char smem[2 * LDSA_BYTES + 2 * LDSB_BYTES]; // 61440 B
    __shared__ float red_m[2][2], red_s[2][2], part_s[2][2][20];

    const int tid  = threadIdx.x;
    const int wv   = tid >> 6;
    const int lane = tid & 63;
    const float* xblk = x + (size_t)blockIdx.x * (256 * 318);

    // staging registers
    float2  ga[16];   // A chunk: fixed s = tid&15, rows j*16 + (tid>>4)
    floatx4 gb[3];    // B chunk: linear copy, 640 float4 per chunk
    const int sA = tid & 15;
    const int rA = tid >> 4;

#define LOADA(c) { _Pragma("unroll") for (int j = 0; j < 16; ++j) { \
        int row = j * 16 + rA; \
        if ((c) == 9 && sA == 15) ga[j] = make_float2(0.f, 0.f); \
        else ga[j] = *(const float2*)(xblk + (size_t)row * 318 + (c) * 32 + sA * 2); } }

#define WRITEA(buf) { char* Ab_ = smem + (buf) * LDSA_BYTES; \
        _Pragma("unroll") for (int j = 0; j < 16; ++j) { \
        int row = j * 16 + rA; \
        uint32_t p = (uint32_t)f32_to_bf16_rne(ga[j].x) | ((uint32_t)f32_to_bf16_rne(ga[j].y) << 16); \
        *(uint32_t*)(Ab_ + row * 80 + sA * 4) = p; } }

#define LOADB(c) { const floatx4* Bf_ = (const floatx4*)Bws + (size_t)(c) * 640; \
        _Pragma("unroll") for (int r = 0; r < 3; ++r) { \
        int f = r * 256 + tid; if (f < 640) gb[r] = Bf_[f]; } }

#define WRITEB(buf) { char* Bb_ = smem + 2 * LDSA_BYTES + (buf) * LDSB_BYTES; \
        _Pragma("unroll") for (int r = 0; r < 3; ++r) { \
        int f = r * 256 + tid; if (f < 640) *(floatx4*)(Bb_ + f * 16) = gb[r]; } }

    floatx4 acc[4][4];
    #pragma unroll
    for (int mi = 0; mi < 4; ++mi)
        #pragma unroll
        for (int nf = 0; nf < 4; ++nf)
            acc[mi][nf] = (floatx4){0.f, 0.f, 0.f, 0.f};

    // prologue
    LOADA(0); LOADB(0);
    WRITEA(0); WRITEB(0);
    LOADA(1); LOADB(1);
    __syncthreads();

    const int fr = lane & 15;   // row/col within fragment
    const int kq = lane >> 4;   // k-quad (8 bf16 each)

    for (int c = 0; c < 10; ++c) {
        const int cur = c & 1;
        if (c < 9) { WRITEA(cur ^ 1); WRITEB(cur ^ 1); }
        if (c < 8) { LOADA(c + 2); LOADB(c + 2); }

        const char* Ab = smem + cur * LDSA_BYTES;
        const char* Bb = smem + 2 * LDSA_BYTES + cur * LDSB_BYTES;

        bf16x8 a[4], bh[4], bl[4];
        #pragma unroll
        for (int mi = 0; mi < 4; ++mi)
            a[mi] = *(const bf16x8*)(Ab + (wv * 64 + mi * 16 + fr) * 80 + kq * 16);
        #pragma unroll
        for (int nf = 0; nf < 4; ++nf) {
            int n = nf * 16 + fr;
            bh[nf] = *(const bf16x8*)(Bb + n * 80 + kq * 16);
            bl[nf] = *(const bf16x8*)(Bb + 5120 + n * 80 + kq * 16);
        }
        #pragma unroll
        for (int mi = 0; mi < 4; ++mi)
            #pragma unroll
            for (int nf = 0; nf < 4; ++nf) {
                acc[mi][nf] = __builtin_amdgcn_mfma_f32_16x16x32_bf16(a[mi], bh[nf], acc[mi][nf], 0, 0, 0);
                acc[mi][nf] = __builtin_amdgcn_mfma_f32_16x16x32_bf16(a[mi], bl[nf], acc[mi][nf], 0, 0, 0);
            }
        __syncthreads();
    }

    // ---- epilogue: bias + ReLU, h1 -> LDS (reuse staging memory), [256][52] f32
    float* h1 = (float*)smem;
    #pragma unroll
    for (int mi = 0; mi < 4; ++mi)
        #pragma unroll
        for (int nf = 0; nf < 4; ++nf) {
            int n = nf * 16 + fr;
            if (n < 50) {
                float bia = b1a[n];
                #pragma unroll
                for (int r = 0; r < 4; ++r) {
                    int m = wv * 64 + mi * 16 + kq * 4 + r;
                    h1[m * 52 + n] = fmaxf(acc[mi][nf][r] + bia, 0.0f);
                }
            }
        }
    __syncthreads();

    // ---- per-token phase (thread t = token t), fp32 VALU
    float hv[50];
    {
        const float* h1row = h1 + tid * 52;
        #pragma unroll
        for (int i = 0; i < 50; ++i) hv[i] = h1row[i];
    }

    float h2[20];
    #pragma unroll
    for (int o = 0; o < 20; ++o) {
        float a = b1b[o];
        const float* w = W1b + o * 50;
        #pragma unroll
        for (int i = 0; i < 50; ++i) a = fmaf(hv[i], w[i], a);
        h2[o] = fmaxf(a, 0.0f);
    }

    float h3[20];
    #pragma unroll
    for (int o = 0; o < 20; ++o) {
        float a = b1c[o];
        const float* w = W1c + o * 20;
        #pragma unroll
        for (int i = 0; i < 20; ++i) a = fmaf(h2[i], w[i], a);
        h3[o] = fmaxf(a, 0.0f);
    }

    float s = pb2[0];
    #pragma unroll
    for (int j = 0; j < 10; ++j) {
        float a = pb1[j];
        const float* w = pW1 + j * 20;
        #pragma unroll
        for (int i = 0; i < 20; ++i) a = fmaf(h3[i], w[i], a);
        s = fmaf(fmaxf(a, 0.0f), pW2[j], s);
    }

    // ---- softmax over T=128 (group = half block = 2 waves)
    const int grp = tid >> 7;
    const int wig = (tid >> 6) & 1;

    float m = s;
    #pragma unroll
    for (int d = 32; d > 0; d >>= 1) m = fmaxf(m, __shfl_xor(m, d));
    if (lane == 0) red_m[grp][wig] = m;
    __syncthreads();
    m = fmaxf(red_m[grp][0], red_m[grp][1]);

    float e = expf(s - m);
    float su = e;
    #pragma unroll
    for (int d = 32; d > 0; d >>= 1) su += __shfl_xor(su, d);
    if (lane == 0) red_s[grp][wig] = su;

    #pragma unroll
    for (int o = 0; o < 20; ++o) {
        float v = e * h3[o];
        #pragma unroll
        for (int d = 32; d > 0; d >>= 1) v += __shfl_xor(v, d);
        if (lane == 0) part_s[grp][wig][o] = v;
    }
    __syncthreads();

    if ((tid & 127) < 20) {
        int o = tid & 127;
        float den = red_s[grp][0] + red_s[grp][1];
        float num = part_s[grp][0][o] + part_s[grp][1][o];
        rout[(size_t)(blockIdx.x * 2 + grp) * 20 + o] = num / den;
    }
#undef LOADA
#undef WRITEA
#undef LOADB
#undef WRITEB
}

// ---------------------------------------------------------------------------
// Kernel B: pooling over G=128, L2-normalize, model3 head. (unchanged)
// ---------------------------------------------------------------------------
__global__ __launch_bounds__(128, 4)
void pool_g_head(const float* __restrict__ r,
                 const float* __restrict__ qW1, const float* __restrict__ qb1,
                 const float* __restrict__ qW2, const float* __restrict__ qb2,
                 const float* __restrict__ W3a, const float* __restrict__ b3a,
                 const float* __restrict__ W3b, const float* __restrict__ b3b,
                 float* __restrict__ out)
{
    __shared__ float red_m[2];
    __shared__ float red_s[2];
    __shared__ float part[2][20];

    const int tid = threadIdx.x;
    const int b = blockIdx.x;
    const float* rr = r + ((size_t)b * 128 + tid) * 20;

    float v[20];
    #pragma unroll
    for (int i = 0; i < 5; ++i) {
        float4 t = *(const float4*)(rr + 4 * i);
        v[4 * i] = t.x; v[4 * i + 1] = t.y; v[4 * i + 2] = t.z; v[4 * i + 3] = t.w;
    }

    float s = qb2[0];
    #pragma unroll
    for (int j = 0; j < 10; ++j) {
        float a = qb1[j];
        const float* w = qW1 + j * 20;
        #pragma unroll
        for (int i = 0; i < 20; ++i) a = fmaf(v[i], w[i], a);
        s = fmaf(fmaxf(a, 0.0f), qW2[j], s);
    }

    const int wig = tid >> 6, lane = tid & 63;
    float m = s;
    #pragma unroll
    for (int d = 32; d > 0; d >>= 1) m = fmaxf(m, __shfl_xor(m, d));
    if (lane == 0) red_m[wig] = m;
    __syncthreads();
    m = fmaxf(red_m[0], red_m[1]);

    float e = expf(s - m);
    float su = e;
    #pragma unroll
    for (int d = 32; d > 0; d >>= 1) su += __shfl_xor(su, d);
    if (lane == 0) red_s[wig] = su;

    #pragma unroll
    for (int o = 0; o < 20; ++o) {
        float val = e * v[o];
        #pragma unroll
        for (int d = 32; d > 0; d >>= 1) val += __shfl_xor(val, d);
        if (lane == 0) part[wig][o] = val;
    }
    __syncthreads();

    if (tid == 0) {
        float den = red_s[0] + red_s[1];
        float rb[20];
        float n2 = 0.0f;
        #pragma unroll
        for (int o = 0; o < 20; ++o) {
            rb[o] = (part[0][o] + part[1][o]) / den;
            n2 = fmaf(rb[o], rb[o], n2);
        }
        float nrm = fmaxf(sqrtf(n2), 1e-12f);
        #pragma unroll
        for (int o = 0; o < 20; ++o) rb[o] /= nrm;

        float accv = b3b[0];
        #pragma unroll
        for (int j = 0; j < 10; ++j) {
            float a = b3a[j];
            const float* w = W3a + j * 20;
            #pragma unroll
            for (int i = 0; i < 20; ++i) a = fmaf(rb[i], w[i], a);
            accv = fmaf(fmaxf(a, 0.0f), W3b[j], accv);
        }
        out[b] = accv;
    }
}

extern "C" void kernel_launch(void* const* d_in, const int* in_sizes, int n_in,
                              void* d_out, int out_size, void* d_ws, size_t ws_size,
                              hipStream_t stream) {
    const float* x   = (const float*)d_in[0];
    const float* W1a = (const float*)d_in[1];
    const float* b1a = (const float*)d_in[2];
    const float* W1b = (const float*)d_in[3];
    const float* b1b = (const float*)d_in[4];
    const float* W1c = (const float*)d_in[5];
    const float* b1c = (const float*)d_in[6];
    const float* pW1 = (const float*)d_in[7];
    const float* pb1 = (const float*)d_in[8];
    const float* pW2 = (const float*)d_in[9];
    const float* pb2 = (const float*)d_in[10];
    const float* qW1 = (const float*)d_in[11];
    const float* qb1 = (const float*)d_in[12];
    const float* qW2 = (const float*)d_in[13];
    const float* qb2 = (const float*)d_in[14];
    const float* W3a = (const float*)d_in[15];
    const float* b3a = (const float*)d_in[16];
    const float* W3b = (const float*)d_in[17];
    const float* b3b = (const float*)d_in[18];

    float* rws = (float*)d_ws;                                    // 327,680 B
    unsigned short* Bws = (unsigned short*)((char*)d_ws + 327680); // 102,400 B

    prep_w<<<1, 256, 0, stream>>>(W1a, Bws);
    fused_mlp_pool_t<<<2048, 256, 0, stream>>>(
        x, Bws, b1a, W1b, b1b, W1c, b1c, pW1, pb1, pW2, pb2, rws);
    pool_g_head<<<32, 128, 0, stream>>>(
        rws, qW1, qb1, qW2, qb2, W3a, b3a, W3b, b3b, (float*)d_out);
}

// Round 3
// 336.553 us; speedup vs baseline: 1.7211x; 1.0504x over previous
//
#include <hip/hip_runtime.h>
#include <math.h>
#include <stdint.h>

typedef __attribute__((ext_vector_type(8))) short bf16x8;
typedef __attribute__((ext_vector_type(4))) float floatx4;

static __device__ __forceinline__ unsigned short f32_to_bf16_rne(float f) {
    union { float f; uint32_t u; } v; v.f = f;
    uint32_t u = v.u;
    return (unsigned short)((u + 0x7fffu + ((u >> 16) & 1u)) >> 16);
}
static __device__ __forceinline__ float bf16_to_f32(unsigned short h) {
    union { uint32_t u; float f; } v; v.u = ((uint32_t)h) << 16;
    return v.f;
}

// ---------------------------------------------------------------------------
// Prep: W1a (50x318) -> hi/lo bf16, fragment-ordered for direct global reads:
// Bpre[ks][part][kq][n][8 bf16]; idx = (((ks*2+p)*4+kq)*64+n)*8+e; 40960 elems.
// ---------------------------------------------------------------------------
__global__ void prep_w(const float* __restrict__ W1a, unsigned short* __restrict__ Bpre) {
    int idx = blockIdx.x * 256 + threadIdx.x;
    if (idx >= 40960) return;
    int e  = idx & 7;
    int n  = (idx >> 3) & 63;
    int kq = (idx >> 9) & 3;
    int p  = (idx >> 11) & 1;
    int ks = idx >> 12;
    int k  = ks * 32 + kq * 8 + e;
    float w = (n < 50 && k < 318) ? W1a[n * 318 + k] : 0.0f;
    unsigned short hi = f32_to_bf16_rne(w);
    Bpre[idx] = (p == 0) ? hi : f32_to_bf16_rne(w - bf16_to_f32(hi));
}

// ---------------------------------------------------------------------------
// Kernel A: 64 tokens/block (one contiguous 80KB x-slab), 8192 blocks,
// 256 threads (4 waves, wave tile = 16 rows x 64 n).
// Layer1 via bf16 MFMA (W hi+lo), layers 2/3 + score + half-group softmax
// partial on wave 0. Partial (m, S, V[20]) -> ws.
// ---------------------------------------------------------------------------
#define LSTR 656   // LDS row stride bytes (328 bf16)

__global__ __launch_bounds__(256, 3)
void fused_mlp_half(const float* __restrict__ x,
                    const unsigned short* __restrict__ Bpre,
                    const float* __restrict__ b1a,
                    const float* __restrict__ W1b, const float* __restrict__ b1b,
                    const float* __restrict__ W1c, const float* __restrict__ b1c,
                    const float* __restrict__ pW1, const float* __restrict__ pb1,
                    const float* __restrict__ pW2, const float* __restrict__ pb2,
                    float* __restrict__ partials)
{
    __shared__ __align__(16) char smem[64 * LSTR];   // 41,984 B

    const int tid  = threadIdx.x;
    const int wv   = tid >> 6;
    const int lane = tid & 63;
    const int fr   = lane & 15;
    const int kq   = lane >> 4;

    const float* slab = x + (size_t)blockIdx.x * (64 * 318);

    // ---- stage: 10176 float2 linear (fully coalesced), cvt -> bf16 LDS
    float2 g[40];
    #pragma unroll
    for (int q = 0; q < 40; ++q) {
        int f = q * 256 + tid;
        g[q] = (f < 10176) ? *(const float2*)(slab + 2 * f) : make_float2(0.f, 0.f);
    }
    #pragma unroll
    for (int q = 0; q < 40; ++q) {
        int f = q * 256 + tid;
        if (f < 10176) {
            int row = f / 159;            // magic-mul
            int c2  = f - row * 159;
            uint32_t pk = (uint32_t)f32_to_bf16_rne(g[q].x) |
                          ((uint32_t)f32_to_bf16_rne(g[q].y) << 16);
            *(uint32_t*)(smem + row * LSTR + c2 * 4) = pk;
        }
    }
    // zero k = 318,319 pad (avoid NaN*0 in MFMA)
    if (tid < 64) *(uint32_t*)(smem + tid * LSTR + 636) = 0u;
    __syncthreads();

    // ---- 10 K-steps: A from LDS, B (hi+lo) straight from L2-resident global
    floatx4 acc[4];
    #pragma unroll
    for (int nf = 0; nf < 4; ++nf) acc[nf] = (floatx4){0.f, 0.f, 0.f, 0.f};

    const char* abase = smem + (wv * 16 + fr) * LSTR + kq * 16;
    const char* bbase = (const char*)Bpre + kq * 1024 + fr * 16;

    #pragma unroll
    for (int ks = 0; ks < 10; ++ks) {
        bf16x8 a = *(const bf16x8*)(abase + ks * 64);
        #pragma unroll
        for (int nf = 0; nf < 4; ++nf) {
            bf16x8 bh = *(const bf16x8*)(bbase + ks * 8192 + nf * 256);
            bf16x8 bl = *(const bf16x8*)(bbase + ks * 8192 + 4096 + nf * 256);
            acc[nf] = __builtin_amdgcn_mfma_f32_16x16x32_bf16(a, bh, acc[nf], 0, 0, 0);
            acc[nf] = __builtin_amdgcn_mfma_f32_16x16x32_bf16(a, bl, acc[nf], 0, 0, 0);
        }
    }
    __syncthreads();   // all LDS-A reads done before overwrite

    // ---- bias + ReLU -> h1 [64][52] f32 in LDS (reuses A buffer)
    float* h1 = (float*)smem;
    #pragma unroll
    for (int nf = 0; nf < 4; ++nf) {
        int n = nf * 16 + fr;
        if (n < 50) {
            float bia = b1a[n];
            #pragma unroll
            for (int r = 0; r < 4; ++r) {
                int m = wv * 16 + kq * 4 + r;     // D row = (lane>>4)*4 + reg
                h1[m * 52 + n] = fmaxf(acc[nf][r] + bia, 0.0f);
            }
        }
    }
    __syncthreads();

    if (wv != 0) return;   // waves 1-3 done; no further barriers

    // ---- wave 0: token t = lane; layers 2/3, score, half-group softmax partial
    float hv[52];
    {
        const float4* h1row = (const float4*)(h1 + lane * 52);
        #pragma unroll
        for (int j = 0; j < 13; ++j) {
            float4 t = h1row[j];
            hv[4 * j] = t.x; hv[4 * j + 1] = t.y; hv[4 * j + 2] = t.z; hv[4 * j + 3] = t.w;
        }
    }

    float h2[20];
    #pragma unroll
    for (int o = 0; o < 20; ++o) {
        float a = b1b[o];
        const float* w = W1b + o * 50;
        #pragma unroll
        for (int i = 0; i < 50; ++i) a = fmaf(hv[i], w[i], a);
        h2[o] = fmaxf(a, 0.0f);
    }

    float h3[20];
    #pragma unroll
    for (int o = 0; o < 20; ++o) {
        float a = b1c[o];
        const float* w = W1c + o * 20;
        #pragma unroll
        for (int i = 0; i < 20; ++i) a = fmaf(h2[i], w[i], a);
        h3[o] = fmaxf(a, 0.0f);
    }

    float s = pb2[0];
    #pragma unroll
    for (int j = 0; j < 10; ++j) {
        float a = pb1[j];
        const float* w = pW1 + j * 20;
        #pragma unroll
        for (int i = 0; i < 20; ++i) a = fmaf(h3[i], w[i], a);
        s = fmaf(fmaxf(a, 0.0f), pW2[j], s);
    }

    // softmax partial over the 64 tokens of this half-group (full wave)
    float m = s;
    #pragma unroll
    for (int d = 32; d > 0; d >>= 1) m = fmaxf(m, __shfl_xor(m, d));

    float e = expf(s - m);
    float S = e;
    #pragma unroll
    for (int d = 32; d > 0; d >>= 1) S += __shfl_xor(S, d);

    float V[20];
    #pragma unroll
    for (int o = 0; o < 20; ++o) {
        float v = e * h3[o];
        #pragma unroll
        for (int d = 32; d > 0; d >>= 1) v += __shfl_xor(v, d);
        V[o] = v;   // all lanes hold the total
    }

    // lanes 0..21 write {m, S, V[0..19]} as one coalesced 88B burst
    float myv = m;
    if (lane == 1) myv = S;
    #pragma unroll
    for (int o = 0; o < 20; ++o) if (lane == o + 2) myv = V[o];
    if (lane < 22) partials[(size_t)blockIdx.x * 24 + lane] = myv;
}

// ---------------------------------------------------------------------------
// Kernel B: combine half-group partials -> r (4096x20), pool over G=128,
// L2-normalize, model3 head. Grid: 32 blocks x 128 threads.
// ---------------------------------------------------------------------------
__global__ __launch_bounds__(128, 4)
void pool_g_head(const float* __restrict__ partials,
                 const float* __restrict__ qW1, const float* __restrict__ qb1,
                 const float* __restrict__ qW2, const float* __restrict__ qb2,
                 const float* __restrict__ W3a, const float* __restrict__ b3a,
                 const float* __restrict__ W3b, const float* __restrict__ b3b,
                 float* __restrict__ out)
{
    __shared__ float red_m[2];
    __shared__ float red_s[2];
    __shared__ float part[2][20];

    const int tid = threadIdx.x;      // g
    const int b = blockIdx.x;
    const float* P = partials + ((size_t)(b * 128 + tid)) * 48;

    // merge the two 64-token halves (exact softmax algebra)
    float m0 = P[0], S0 = P[1], m1 = P[24], S1 = P[25];
    float m = fmaxf(m0, m1);
    float w0 = expf(m0 - m), w1 = expf(m1 - m);
    float den = fmaf(S0, w0, S1 * w1);

    float v[20];
    #pragma unroll
    for (int o = 0; o < 20; ++o)
        v[o] = fmaf(P[2 + o], w0, P[26 + o] * w1) / den;

    float s = qb2[0];
    #pragma unroll
    for (int j = 0; j < 10; ++j) {
        float a = qb1[j];
        const float* w = qW1 + j * 20;
        #pragma unroll
        for (int i = 0; i < 20; ++i) a = fmaf(v[i], w[i], a);
        s = fmaf(fmaxf(a, 0.0f), qW2[j], s);
    }

    const int wig = tid >> 6, lane = tid & 63;
    float mm = s;
    #pragma unroll
    for (int d = 32; d > 0; d >>= 1) mm = fmaxf(mm, __shfl_xor(mm, d));
    if (lane == 0) red_m[wig] = mm;
    __syncthreads();
    mm = fmaxf(red_m[0], red_m[1]);

    float e = expf(s - mm);
    float su = e;
    #pragma unroll
    for (int d = 32; d > 0; d >>= 1) su += __shfl_xor(su, d);
    if (lane == 0) red_s[wig] = su;

    #pragma unroll
    for (int o = 0; o < 20; ++o) {
        float val = e * v[o];
        #pragma unroll
        for (int d = 32; d > 0; d >>= 1) val += __shfl_xor(val, d);
        if (lane == 0) part[wig][o] = val;
    }
    __syncthreads();

    if (tid == 0) {
        float dg = red_s[0] + red_s[1];
        float rb[20];
        float n2 = 0.0f;
        #pragma unroll
        for (int o = 0; o < 20; ++o) {
            rb[o] = (part[0][o] + part[1][o]) / dg;
            n2 = fmaf(rb[o], rb[o], n2);
        }
        float nrm = fmaxf(sqrtf(n2), 1e-12f);
        #pragma unroll
        for (int o = 0; o < 20; ++o) rb[o] /= nrm;

        float accv = b3b[0];
        #pragma unroll
        for (int j = 0; j < 10; ++j) {
            float a = b3a[j];
            const float* w = W3a + j * 20;
            #pragma unroll
            for (int i = 0; i < 20; ++i) a = fmaf(rb[i], w[i], a);
            accv = fmaf(fmaxf(a, 0.0f), W3b[j], accv);
        }
        out[b] = accv;
    }
}

extern "C" void kernel_launch(void* const* d_in, const int* in_sizes, int n_in,
                              void* d_out, int out_size, void* d_ws, size_t ws_size,
                              hipStream_t stream) {
    const float* x   = (const float*)d_in[0];
    const float* W1a = (const float*)d_in[1];
    const float* b1a = (const float*)d_in[2];
    const float* W1b = (const float*)d_in[3];
    const float* b1b = (const float*)d_in[4];
    const float* W1c = (const float*)d_in[5];
    const float* b1c = (const float*)d_in[6];
    const float* pW1 = (const float*)d_in[7];
    const float* pb1 = (const float*)d_in[8];
    const float* pW2 = (const float*)d_in[9];
    const float* pb2 = (const float*)d_in[10];
    const float* qW1 = (const float*)d_in[11];
    const float* qb1 = (const float*)d_in[12];
    const float* qW2 = (const float*)d_in[13];
    const float* qb2 = (const float*)d_in[14];
    const float* W3a = (const float*)d_in[15];
    const float* b3a = (const float*)d_in[16];
    const float* W3b = (const float*)d_in[17];
    const float* b3b = (const float*)d_in[18];

    float* partials     = (float*)d_ws;                              // 8192*24*4 = 786,432 B
    unsigned short* Bpre = (unsigned short*)((char*)d_ws + 786432);  // 81,920 B

    prep_w<<<160, 256, 0, stream>>>(W1a, Bpre);
    fused_mlp_half<<<8192, 256, 0, stream>>>(
        x, Bpre, b1a, W1b, b1b, W1c, b1c, pW1, pb1, pW2, pb2, partials);
    pool_g_head<<<32, 128, 0, stream>>>(
        partials, qW1, qb1, qW2, qb2, W3a, b3a, W3b, b3b, (float*)d_out);
}